// Round 11
// baseline (134.070 us; speedup 1.0000x reference)
//
#include <hip/hip_runtime.h>

#define D 128
#define BN_EPS 1e-5f
#define ROWS 16
#define CHUNK 8192      // edges per partition block
#define CAP_SCAN 256    // max chunks supported by scanB1 (E <= 256*8192)
#define HSTRIDE 136     // LDS row stride in u16 (16B-aligned, bank-conflict-free)

typedef unsigned int u32;
typedef unsigned short u16;
typedef __attribute__((ext_vector_type(8))) __bf16 bf16x8;
typedef __attribute__((ext_vector_type(4))) float f32x4;

// ---- pack two floats to bf16x2 (RNE) ----
__device__ inline u32 pk_bf16(float x, float y) {
    u32 ux = __float_as_uint(x), uy = __float_as_uint(y);
    ux = (ux + 0x7fffu + ((ux >> 16) & 1u)) >> 16;
    uy = (uy + 0x7fffu + ((uy >> 16) & 1u)) >> 16;
    return ux | (uy << 16);
}

// ------- prep: cast feature->bf16 | pack W into MFMA B-fragment order | hist -
// Wb slot ((ct*4+ks)*64+l)*8+i = bf16( W[16ct+(l&15)][ks*32+(l>>4)*8+i] )
__global__ __launch_bounds__(256) void prep(const float* __restrict__ feat,
                                            u16* __restrict__ feat16,
                                            const float* __restrict__ W,
                                            u16* __restrict__ Wb,
                                            const int* __restrict__ dst,
                                            int* __restrict__ blkcnt,
                                            int ncast, int nch, int nedges) {
    __shared__ int cnt[256];
    const int b = blockIdx.x;
    if (b < ncast) {
        size_t i = ((size_t)b * 256 + threadIdx.x) * 8;
        float4 f0 = *reinterpret_cast<const float4*>(feat + i);
        float4 f1 = *reinterpret_cast<const float4*>(feat + i + 4);
        uint4 o;
        o.x = pk_bf16(f0.x, f0.y);
        o.y = pk_bf16(f0.z, f0.w);
        o.z = pk_bf16(f1.x, f1.y);
        o.w = pk_bf16(f1.z, f1.w);
        *reinterpret_cast<uint4*>(feat16 + i) = o;
    } else if (b < ncast + 8) {
        int t = (b - ncast) * 256 + threadIdx.x;   // 0..2047, one fragment each
        int ct = t >> 8;
        int ks = (t >> 6) & 3;
        int l = t & 63;
        int row_w = 16 * ct + (l & 15);
        int col0 = ks * 32 + (l >> 4) * 8;
        float4 f0 = *reinterpret_cast<const float4*>(W + row_w * D + col0);
        float4 f1 = *reinterpret_cast<const float4*>(W + row_w * D + col0 + 4);
        uint4 o;
        o.x = pk_bf16(f0.x, f0.y);
        o.y = pk_bf16(f0.z, f0.w);
        o.z = pk_bf16(f1.x, f1.y);
        o.w = pk_bf16(f1.z, f1.w);
        *reinterpret_cast<uint4*>(Wb + (size_t)t * 8) = o;
    } else {
        const int c = b - ncast - 8;               // chunk index
        cnt[threadIdx.x] = 0;
        __syncthreads();
        const int e0 = c * CHUNK;
        for (int r = 0; r < CHUNK / 256; ++r) {
            int e = e0 + r * 256 + threadIdx.x;
            if (e < nedges) atomicAdd(&cnt[dst[e] >> 8], 1);
        }
        __syncthreads();
        blkcnt[(size_t)threadIdx.x * nch + c] = cnt[threadIdx.x];
    }
}

// ------- scanB1: per-bucket exclusive scan over chunks (in place) ------------
__global__ __launch_bounds__(CAP_SCAN) void scanB1(int* __restrict__ blkcnt,
                                                   int* __restrict__ gtot,
                                                   int nch) {
    __shared__ int s[CAP_SCAN];
    const int t = threadIdx.x;
    const size_t row = (size_t)blockIdx.x * nch;
    int v = (t < nch) ? blkcnt[row + t] : 0;
    s[t] = v;
    __syncthreads();
    for (int off = 1; off < CAP_SCAN; off <<= 1) {
        int u = (t >= off) ? s[t - off] : 0;
        __syncthreads();
        s[t] += u;
        __syncthreads();
    }
    if (t < nch) blkcnt[row + t] = s[t] - v;   // exclusive within bucket
    if (t == 0) gtot[blockIdx.x] = s[CAP_SCAN - 1];
}

// ------- scanB2: exclusive scan of 256 bucket totals (1 block) ---------------
__global__ __launch_bounds__(256) void scanB2(const int* __restrict__ gtot,
                                              int* __restrict__ bucket_base,
                                              int* __restrict__ bucket_cnt) {
    __shared__ int s[256];
    const int t = threadIdx.x;
    int v = gtot[t];
    s[t] = v;
    __syncthreads();
    for (int off = 1; off < 256; off <<= 1) {
        int u = (t >= off) ? s[t - off] : 0;
        __syncthreads();
        s[t] += u;
        __syncthreads();
    }
    bucket_base[t] = s[t] - v;
    bucket_cnt[t] = v;
}

// ------- passB: partition edges into buckets (deterministic bases, LDS cnt) --
__global__ __launch_bounds__(512) void passB(const int* __restrict__ src,
                                             const int* __restrict__ dst,
                                             const int* __restrict__ blkcnt,
                                             const int* __restrict__ bucket_base,
                                             u32* __restrict__ gpacked,
                                             int nch, int nedges) {
    __shared__ int cnt[256];
    __shared__ int gbase[256];
    const int t = threadIdx.x;
    if (t < 256) {
        gbase[t] = blkcnt[(size_t)t * nch + blockIdx.x] + bucket_base[t];
        cnt[t] = 0;
    }
    __syncthreads();
    const int e0 = blockIdx.x * CHUNK;
    for (int r = 0; r < CHUNK / 512; ++r) {
        int e = e0 + r * 512 + t;
        if (e < nedges) {
            int d = dst[e];
            int b = d >> 8;
            int pos = atomicAdd(&cnt[b], 1);
            gpacked[gbase[b] + pos] = (u32)src[e] | ((u32)(d & 255) << 16);
        }
    }
}

// ------- pass2: per-bucket counting sort by dst low byte (512 threads) -------
__global__ __launch_bounds__(512) void pass2(const u32* __restrict__ gpacked,
                                             const int* __restrict__ bucket_base,
                                             const int* __restrict__ bucket_cnt,
                                             u16* __restrict__ epos,
                                             int* __restrict__ count,
                                             int* __restrict__ offs,
                                             int nnodes) {
    __shared__ int cnt[256], lo[256], cur[256];
    const int t = threadIdx.x;
    const int b = blockIdx.x;
    const int nE = bucket_cnt[b];
    const int base = bucket_base[b];
    if (t < 256) cnt[t] = 0;
    __syncthreads();
    for (int i = t; i < nE; i += 512) atomicAdd(&cnt[gpacked[base + i] >> 16], 1);
    __syncthreads();
    int v = (t < 256) ? cnt[t] : 0;
    if (t < 256) lo[t] = v;
    __syncthreads();
    for (int off = 1; off < 256; off <<= 1) {
        int u = (t >= off && t < 256) ? lo[t - off] : 0;
        __syncthreads();
        if (t < 256) lo[t] += u;
        __syncthreads();
    }
    if (t < 256) {
        int excl = lo[t] - v;
        int n = (b << 8) + t;
        if (n < nnodes) { count[n] = v; offs[n] = base + excl; }
        cur[t] = excl;
    }
    __syncthreads();
    for (int i = t; i < nE; i += 512) {
        u32 p = gpacked[base + i];
        int pos = atomicAdd(&cur[p >> 16], 1);
        epos[base + pos] = (u16)(p & 0xffffu);
    }
}

// ---------------- fused: mean-aggregate (bf16 CSR gather) -> LDS(bf16) ->
//                  MFMA linear -> graph-norm -> BN partials ------------------
// 256 threads = 4 waves. Each QUARTER-wave (16 lanes = one 256B bf16 row) owns
// one node: 4 independent gather chains per wave, no cross-lane reduction.
// Phase 2: per wave two 16x16 MFMA output tiles.
__global__ __launch_bounds__(256, 8) void fused_agg_linear(
        const float* __restrict__ feat,
        const u16* __restrict__ feat16,
        const float* __restrict__ snorm,
        const int* __restrict__ offs,
        const int* __restrict__ count,
        const u16* __restrict__ epos,
        const u16* __restrict__ Wb,
        const float* __restrict__ bias,
        float* __restrict__ y,
        float* __restrict__ partial) {
    __shared__ u16 hs16[ROWS][HSTRIDE];   // 4.25 KB, bf16 h-tile
    const int row0 = blockIdx.x * ROWS;
    const int wid = threadIdx.x >> 6;
    const int lane = threadIdx.x & 63;
    const int q = lane >> 4;      // quarter 0..3
    const int ql = lane & 15;     // lane within quarter; covers cols 8*ql..8*ql+7

#define LDB(s) (*reinterpret_cast<const uint4*>(feat16 + (size_t)(s) * D + 8 * ql))
#define ADD8(a, u) { \
    a[0] += __uint_as_float((u).x << 16); a[1] += __uint_as_float((u).x & 0xffff0000u); \
    a[2] += __uint_as_float((u).y << 16); a[3] += __uint_as_float((u).y & 0xffff0000u); \
    a[4] += __uint_as_float((u).z << 16); a[5] += __uint_as_float((u).z & 0xffff0000u); \
    a[6] += __uint_as_float((u).w << 16); a[7] += __uint_as_float((u).w & 0xffff0000u); }

    // ---- phase 1: aggregation, one node per quarter-wave ----
    {
        const int r = wid * 4 + q;      // this quarter's row in the tile
        const int n = row0 + r;
        const int dg = count[n];
        const u16* ep = epos + offs[n];
        float a0[8], a1[8];
        #pragma unroll
        for (int k = 0; k < 8; ++k) { a0[k] = 0.0f; a1[k] = 0.0f; }

        int j = 0;
        for (; j + 2 <= dg; j += 2) {
            int s0 = (int)ep[j];
            int s1 = (int)ep[j + 1];
            uint4 u0 = LDB(s0);
            uint4 u1 = LDB(s1);
            ADD8(a0, u0);
            ADD8(a1, u1);
        }
        if (j < dg) {
            uint4 u0 = LDB((int)ep[j]);
            ADD8(a0, u0);
        }

        float av[8];
        if (dg > 0) {
            float inv = 1.0f / (float)dg;
            #pragma unroll
            for (int k = 0; k < 8; ++k) av[k] = (a0[k] + a1[k]) * inv;
        } else {
            float4 f0 = *reinterpret_cast<const float4*>(feat + (size_t)n * D + 8 * ql);
            float4 f1 = *reinterpret_cast<const float4*>(feat + (size_t)n * D + 8 * ql + 4);
            av[0] = f0.x; av[1] = f0.y; av[2] = f0.z; av[3] = f0.w;
            av[4] = f1.x; av[5] = f1.y; av[6] = f1.z; av[7] = f1.w;
        }
        uint4 o4;
        o4.x = pk_bf16(av[0], av[1]);
        o4.y = pk_bf16(av[2], av[3]);
        o4.z = pk_bf16(av[4], av[5]);
        o4.w = pk_bf16(av[6], av[7]);
        *reinterpret_cast<uint4*>(&hs16[r][8 * ql]) = o4;
    }
#undef LDB
#undef ADD8
    __syncthreads();

    // ---- phase 2: MFMA linear. wave wid handles col-tiles 2*wid, 2*wid+1 ----
    // A frag (16x32 per K-step): lane holds hs16[lane&15][ks*32+(lane>>4)*8 ..+7]
    bf16x8 afrag[4];
    const int arow = lane & 15;
    const int acol0 = (lane >> 4) * 8;
    #pragma unroll
    for (int ks = 0; ks < 4; ++ks)
        afrag[ks] = *reinterpret_cast<const bf16x8*>(&hs16[arow][ks * 32 + acol0]);

    #pragma unroll
    for (int c2 = 0; c2 < 2; ++c2) {
        const int ct = wid * 2 + c2;
        f32x4 acc = {0.f, 0.f, 0.f, 0.f};
        #pragma unroll
        for (int ks = 0; ks < 4; ++ks) {
            bf16x8 bfrag = *reinterpret_cast<const bf16x8*>(
                Wb + ((size_t)(ct * 4 + ks) * 64 + lane) * 8);
            acc = __builtin_amdgcn_mfma_f32_16x16x32_bf16(afrag[ks], bfrag, acc, 0, 0, 0);
        }
        const int col = ct * 16 + (lane & 15);
        const float bb = bias[col];
        float psum = 0.0f, psq = 0.0f;
        #pragma unroll
        for (int i = 0; i < 4; ++i) {
            const int rrow = (lane >> 4) * 4 + i;   // C/D row mapping (m89)
            const int n = row0 + rrow;
            float v = (acc[i] + bb) * snorm[n];
            y[(size_t)n * D + col] = v;
            psum += v;
            psq += v * v;
        }
        psum += __shfl_xor(psum, 16, 64);
        psq  += __shfl_xor(psq, 16, 64);
        psum += __shfl_xor(psum, 32, 64);
        psq  += __shfl_xor(psq, 32, 64);
        if (lane < 16) {
            partial[(size_t)blockIdx.x * 256 + col] = psum;
            partial[(size_t)blockIdx.x * 256 + 128 + col] = psq;
        }
    }
}

// ---------------- reduce partials -> BN scale/shift per column ----------------
__global__ __launch_bounds__(256) void bn_reduce(const float* __restrict__ partial,
                                                 const float* __restrict__ gamma,
                                                 const float* __restrict__ beta,
                                                 float* __restrict__ bnparam,
                                                 int nchunk, float inv_n) {
    const int d = blockIdx.x;
    float s = 0.0f, q = 0.0f;
    for (int b = threadIdx.x; b < nchunk; b += 256) {
        s += partial[(size_t)b * 256 + d];
        q += partial[(size_t)b * 256 + 128 + d];
    }
    for (int off = 32; off > 0; off >>= 1) {
        s += __shfl_down(s, off, 64);
        q += __shfl_down(q, off, 64);
    }
    __shared__ float ss[4], qq[4];
    int wid = threadIdx.x >> 6;
    int lane = threadIdx.x & 63;
    if (lane == 0) { ss[wid] = s; qq[wid] = q; }
    __syncthreads();
    if (threadIdx.x == 0) {
        float S = ss[0] + ss[1] + ss[2] + ss[3];
        float Q = qq[0] + qq[1] + qq[2] + qq[3];
        float mu = S * inv_n;
        float var = Q * inv_n - mu * mu;
        var = fmaxf(var, 0.0f);
        float rstd = rsqrtf(var + BN_EPS);
        float scale = gamma[d] * rstd;
        float shift = beta[d] - mu * scale;
        bnparam[d] = scale;
        bnparam[D + d] = shift;
    }
}

// ---------------- finalize: out = feat + relu(y*scale + shift), in place on y --
__global__ __launch_bounds__(256) void finalize(const float* __restrict__ feat,
                                                float* __restrict__ y,
                                                const float* __restrict__ bnparam,
                                                int total4) {
    int i = blockIdx.x * 256 + threadIdx.x;
    if (i >= total4) return;
    int c = i & 31;
    float4 v = reinterpret_cast<float4*>(y)[i];
    float4 f = reinterpret_cast<const float4*>(feat)[i];
    float4 sc = reinterpret_cast<const float4*>(bnparam)[c];
    float4 sh = reinterpret_cast<const float4*>(bnparam + D)[c];
    v.x = f.x + fmaxf(v.x * sc.x + sh.x, 0.0f);
    v.y = f.y + fmaxf(v.y * sc.y + sh.y, 0.0f);
    v.z = f.z + fmaxf(v.z * sc.z + sh.z, 0.0f);
    v.w = f.w + fmaxf(v.w * sc.w + sh.w, 0.0f);
    reinterpret_cast<float4*>(y)[i] = v;
}

extern "C" void kernel_launch(void* const* d_in, const int* in_sizes, int n_in,
                              void* d_out, int out_size, void* d_ws, size_t ws_size,
                              hipStream_t stream) {
    const float* feat  = (const float*)d_in[0];
    const float* snorm = (const float*)d_in[1];
    const int*   src   = (const int*)d_in[2];
    const int*   dst   = (const int*)d_in[3];
    const float* W     = (const float*)d_in[4];
    const float* bias  = (const float*)d_in[5];
    const float* gamma = (const float*)d_in[6];
    const float* beta  = (const float*)d_in[7];

    const int N = in_sizes[1];              // 50000
    const int E = in_sizes[2];              // 1600000
    const int nblk = N / ROWS;              // 3125
    const int nch = (E + CHUNK - 1) / CHUNK;   // 196 (<= CAP_SCAN)
    const int nbuck = (N + 255) >> 8;          // 196
    const int ncast = (N * D) / (8 * 256);     // 3125

    // workspace layout (all segments 16B-aligned)
    int* count       = (int*)d_ws;                          // N
    int* offs        = count + N;                           // N
    int* blkcnt      = offs + N;                            // 256*nch
    int* gtot        = blkcnt + (size_t)256 * nch;          // 256
    int* bucket_base = gtot + 256;                          // 256
    int* bucket_cnt  = bucket_base + 256;                   // 256
    u32* gpacked     = (u32*)(bucket_cnt + 256);            // E
    u16* epos        = (u16*)(gpacked + E);                 // E
    u16* feat16      = epos + E;                            // N*D
    u16* Wb          = feat16 + (size_t)N * D;              // D*D (bf16)
    float* partial   = (float*)(Wb + D * D);                // nblk*256
    float* bnparam   = partial + (size_t)nblk * 256;        // 2*D

    float* y = (float*)d_out;

    prep<<<ncast + 8 + nch, 256, 0, stream>>>(feat, feat16, W, Wb, dst,
                                              blkcnt, ncast, nch, E);

    scanB1<<<256, CAP_SCAN, 0, stream>>>(blkcnt, gtot, nch);
    scanB2<<<1, 256, 0, stream>>>(gtot, bucket_base, bucket_cnt);

    passB<<<nch, 512, 0, stream>>>(src, dst, blkcnt, bucket_base, gpacked, nch, E);

    pass2<<<nbuck, 512, 0, stream>>>(gpacked, bucket_base, bucket_cnt,
                                     epos, count, offs, N);

    fused_agg_linear<<<nblk, 256, 0, stream>>>(feat, feat16, snorm, offs, count,
                                               epos, Wb, bias, y, partial);

    bn_reduce<<<D, 256, 0, stream>>>(partial, gamma, beta, bnparam,
                                     nblk, 1.0f / (float)N);

    {
        int total4 = N * D / 4;
        finalize<<<(total4 + 255) / 256, 256, 0, stream>>>(feat, y, bnparam, total4);
    }
}

// Round 12
// 128.989 us; speedup vs baseline: 1.0394x; 1.0394x over previous
//
#include <hip/hip_runtime.h>

#define D 128
#define BN_EPS 1e-5f
#define ROWS 16
#define CHUNK 8192      // edges per partition block
#define CAP_SCAN 256    // max chunks supported by scanB1 (E <= 256*8192)
#define HSTRIDE 136     // LDS row stride in u16 (16B-aligned, bank-conflict-free)
#define P2CAP 12288     // pass2 LDS staging capacity (mean bucket ~8163, +45 sd)

typedef unsigned int u32;
typedef unsigned short u16;
typedef __attribute__((ext_vector_type(8))) __bf16 bf16x8;
typedef __attribute__((ext_vector_type(4))) float f32x4;

// ---- pack two floats to bf16x2 (RNE) ----
__device__ inline u32 pk_bf16(float x, float y) {
    u32 ux = __float_as_uint(x), uy = __float_as_uint(y);
    ux = (ux + 0x7fffu + ((ux >> 16) & 1u)) >> 16;
    uy = (uy + 0x7fffu + ((uy >> 16) & 1u)) >> 16;
    return ux | (uy << 16);
}

// ------- prep: cast feature->bf16 | pack W into MFMA B-fragment order | hist -
__global__ __launch_bounds__(256) void prep(const float* __restrict__ feat,
                                            u16* __restrict__ feat16,
                                            const float* __restrict__ W,
                                            u16* __restrict__ Wb,
                                            const int* __restrict__ dst,
                                            int* __restrict__ blkcnt,
                                            int ncast, int nch, int nedges) {
    __shared__ int cnt[256];
    const int b = blockIdx.x;
    if (b < ncast) {
        size_t i = ((size_t)b * 256 + threadIdx.x) * 8;
        float4 f0 = *reinterpret_cast<const float4*>(feat + i);
        float4 f1 = *reinterpret_cast<const float4*>(feat + i + 4);
        uint4 o;
        o.x = pk_bf16(f0.x, f0.y);
        o.y = pk_bf16(f0.z, f0.w);
        o.z = pk_bf16(f1.x, f1.y);
        o.w = pk_bf16(f1.z, f1.w);
        *reinterpret_cast<uint4*>(feat16 + i) = o;
    } else if (b < ncast + 8) {
        int t = (b - ncast) * 256 + threadIdx.x;   // 0..2047, one fragment each
        int ct = t >> 8;
        int ks = (t >> 6) & 3;
        int l = t & 63;
        int row_w = 16 * ct + (l & 15);
        int col0 = ks * 32 + (l >> 4) * 8;
        float4 f0 = *reinterpret_cast<const float4*>(W + row_w * D + col0);
        float4 f1 = *reinterpret_cast<const float4*>(W + row_w * D + col0 + 4);
        uint4 o;
        o.x = pk_bf16(f0.x, f0.y);
        o.y = pk_bf16(f0.z, f0.w);
        o.z = pk_bf16(f1.x, f1.y);
        o.w = pk_bf16(f1.z, f1.w);
        *reinterpret_cast<uint4*>(Wb + (size_t)t * 8) = o;
    } else {
        const int c = b - ncast - 8;               // chunk index
        cnt[threadIdx.x] = 0;
        __syncthreads();
        const int e0 = c * CHUNK;
        for (int r = 0; r < CHUNK / 256; ++r) {
            int e = e0 + r * 256 + threadIdx.x;
            if (e < nedges) atomicAdd(&cnt[dst[e] >> 8], 1);
        }
        __syncthreads();
        blkcnt[(size_t)threadIdx.x * nch + c] = cnt[threadIdx.x];
    }
}

// ------- scanB1: per-bucket exclusive scan over chunks (in place) ------------
__global__ __launch_bounds__(CAP_SCAN) void scanB1(int* __restrict__ blkcnt,
                                                   int* __restrict__ gtot,
                                                   int nch) {
    __shared__ int s[CAP_SCAN];
    const int t = threadIdx.x;
    const size_t row = (size_t)blockIdx.x * nch;
    int v = (t < nch) ? blkcnt[row + t] : 0;
    s[t] = v;
    __syncthreads();
    for (int off = 1; off < CAP_SCAN; off <<= 1) {
        int u = (t >= off) ? s[t - off] : 0;
        __syncthreads();
        s[t] += u;
        __syncthreads();
    }
    if (t < nch) blkcnt[row + t] = s[t] - v;   // exclusive within bucket
    if (t == 0) gtot[blockIdx.x] = s[CAP_SCAN - 1];
}

// ------- scanB2: exclusive scan of 256 bucket totals (1 block) ---------------
__global__ __launch_bounds__(256) void scanB2(const int* __restrict__ gtot,
                                              int* __restrict__ bucket_base,
                                              int* __restrict__ bucket_cnt) {
    __shared__ int s[256];
    const int t = threadIdx.x;
    int v = gtot[t];
    s[t] = v;
    __syncthreads();
    for (int off = 1; off < 256; off <<= 1) {
        int u = (t >= off) ? s[t - off] : 0;
        __syncthreads();
        s[t] += u;
        __syncthreads();
    }
    bucket_base[t] = s[t] - v;
    bucket_cnt[t] = v;
}

// ------- passB: partition edges into buckets, LDS-staged coalesced writes ----
__global__ __launch_bounds__(512) void passB(const int* __restrict__ src,
                                             const int* __restrict__ dst,
                                             const int* __restrict__ blkcnt,
                                             const int* __restrict__ bucket_base,
                                             u32* __restrict__ gpacked,
                                             int nch, int nedges) {
    __shared__ u32 sval[CHUNK];      // 32 KB
    __shared__ u16 sbuck[CHUNK];     // 16 KB
    __shared__ int cnt[256], lo[256], gbase[256];
    const int t = threadIdx.x;
    const int e0 = blockIdx.x * CHUNK;
    const int m = min(CHUNK, nedges - e0);
    if (t < 256) {
        cnt[t] = 0;
        gbase[t] = blkcnt[(size_t)t * nch + blockIdx.x] + bucket_base[t];
    }
    __syncthreads();
    for (int k = t; k < m; k += 512) atomicAdd(&cnt[dst[e0 + k] >> 8], 1);
    __syncthreads();
    int v = (t < 256) ? cnt[t] : 0;
    if (t < 256) lo[t] = v;
    __syncthreads();
    for (int off = 1; off < 256; off <<= 1) {
        int u = (t >= off && t < 256) ? lo[t - off] : 0;
        __syncthreads();
        if (t < 256) lo[t] += u;
        __syncthreads();
    }
    if (t < 256) { int ex = lo[t] - v; lo[t] = ex; cnt[t] = ex; }   // cnt = cursor
    __syncthreads();
    for (int k = t; k < m; k += 512) {
        int d = dst[e0 + k];
        int b = d >> 8;
        int p = atomicAdd(&cnt[b], 1);
        sval[p] = (u32)src[e0 + k] | ((u32)(d & 255) << 16);
        sbuck[p] = (u16)b;
    }
    __syncthreads();
    for (int i = t; i < m; i += 512) {
        int b = sbuck[i];
        gpacked[gbase[b] + (i - lo[b])] = sval[i];   // coalesced runs per bucket
    }
}

// ------- pass2: per-bucket counting sort by dst low byte, LDS-staged ---------
__global__ __launch_bounds__(512) void pass2(const u32* __restrict__ gpacked,
                                             const int* __restrict__ bucket_base,
                                             const int* __restrict__ bucket_cnt,
                                             u16* __restrict__ epos,
                                             int* __restrict__ count,
                                             int* __restrict__ offs,
                                             int nnodes) {
    __shared__ u16 sepos[P2CAP];     // 24 KB
    __shared__ int cnt[256], lo[256], cur[256];
    const int t = threadIdx.x;
    const int b = blockIdx.x;
    const int nE = bucket_cnt[b];
    const int base = bucket_base[b];
    if (t < 256) cnt[t] = 0;
    __syncthreads();
    for (int i = t; i < nE; i += 512) atomicAdd(&cnt[gpacked[base + i] >> 16], 1);
    __syncthreads();
    int v = (t < 256) ? cnt[t] : 0;
    if (t < 256) lo[t] = v;
    __syncthreads();
    for (int off = 1; off < 256; off <<= 1) {
        int u = (t >= off && t < 256) ? lo[t - off] : 0;
        __syncthreads();
        if (t < 256) lo[t] += u;
        __syncthreads();
    }
    if (t < 256) {
        int excl = lo[t] - v;
        int n = (b << 8) + t;
        if (n < nnodes) { count[n] = v; offs[n] = base + excl; }
        cur[t] = excl;
    }
    __syncthreads();
    if (nE <= P2CAP) {
        for (int i = t; i < nE; i += 512) {
            u32 p = gpacked[base + i];
            int pos = atomicAdd(&cur[p >> 16], 1);
            sepos[pos] = (u16)(p & 0xffffu);
        }
        __syncthreads();
        for (int i = t; i < nE; i += 512) epos[base + i] = sepos[i];  // coalesced
    } else {
        for (int i = t; i < nE; i += 512) {
            u32 p = gpacked[base + i];
            int pos = atomicAdd(&cur[p >> 16], 1);
            epos[base + pos] = (u16)(p & 0xffffu);
        }
    }
}

// ---------------- fused: mean-aggregate (bf16 CSR gather) -> LDS(bf16) ->
//                  MFMA linear -> graph-norm -> BN partials ------------------
// 256 threads = 4 waves, 4 nodes/wave gather (r9 shape: quarters cooperate,
// epos broadcast loads). Phase 2: per wave two 16x16 MFMA output tiles.
__global__ __launch_bounds__(256, 8) void fused_agg_linear(
        const float* __restrict__ feat,
        const u16* __restrict__ feat16,
        const float* __restrict__ snorm,
        const int* __restrict__ offs,
        const int* __restrict__ count,
        const u16* __restrict__ epos,
        const u16* __restrict__ Wb,
        const float* __restrict__ bias,
        float* __restrict__ y,
        float* __restrict__ partial) {
    __shared__ u16 hs16[ROWS][HSTRIDE];   // 4.25 KB, bf16 h-tile
    const int row0 = blockIdx.x * ROWS;
    const int wid = threadIdx.x >> 6;
    const int lane = threadIdx.x & 63;
    const int q = lane >> 4;      // quarter 0..3
    const int ql = lane & 15;     // lane within quarter; covers cols 8*ql..8*ql+7

#define LDB(s) (*reinterpret_cast<const uint4*>(feat16 + (size_t)(s) * D + 8 * ql))
#define ADD8(a, u) { \
    a[0] += __uint_as_float((u).x << 16); a[1] += __uint_as_float((u).x & 0xffff0000u); \
    a[2] += __uint_as_float((u).y << 16); a[3] += __uint_as_float((u).y & 0xffff0000u); \
    a[4] += __uint_as_float((u).z << 16); a[5] += __uint_as_float((u).z & 0xffff0000u); \
    a[6] += __uint_as_float((u).w << 16); a[7] += __uint_as_float((u).w & 0xffff0000u); }

    // ---- phase 1: aggregation, one wave per node (4 nodes per wave) ----
    for (int rr = 0; rr < 4; ++rr) {
        const int r = wid * 4 + rr;
        const int n = row0 + r;
        const int dg = count[n];
        const u16* ep = epos + offs[n];
        float a0[8], a1[8];
        #pragma unroll
        for (int k = 0; k < 8; ++k) { a0[k] = 0.0f; a1[k] = 0.0f; }

        int j = 0;
        for (; j + 8 <= dg; j += 8) {
            int s0 = (int)ep[j + q];
            int s1 = (int)ep[j + 4 + q];
            uint4 u0 = LDB(s0);
            uint4 u1 = LDB(s1);
            ADD8(a0, u0);
            ADD8(a1, u1);
        }
        {   // tail (<8 edges), quarter-predicated
            int i0 = j + q, i1 = j + 4 + q;
            if (i0 < dg) { uint4 u0 = LDB((int)ep[i0]); ADD8(a0, u0); }
            if (i1 < dg) { uint4 u1 = LDB((int)ep[i1]); ADD8(a1, u1); }
        }

        float av[8];
        #pragma unroll
        for (int k = 0; k < 8; ++k) {
            float v = a0[k] + a1[k];
            v += __shfl_xor(v, 16, 64);
            v += __shfl_xor(v, 32, 64);
            av[k] = v;
        }
        if (dg > 0) {
            float inv = 1.0f / (float)dg;
            #pragma unroll
            for (int k = 0; k < 8; ++k) av[k] *= inv;
        } else {
            float4 f0 = *reinterpret_cast<const float4*>(feat + (size_t)n * D + 8 * ql);
            float4 f1 = *reinterpret_cast<const float4*>(feat + (size_t)n * D + 8 * ql + 4);
            av[0] = f0.x; av[1] = f0.y; av[2] = f0.z; av[3] = f0.w;
            av[4] = f1.x; av[5] = f1.y; av[6] = f1.z; av[7] = f1.w;
        }
        if (q == 0) {
            uint4 o4;
            o4.x = pk_bf16(av[0], av[1]);
            o4.y = pk_bf16(av[2], av[3]);
            o4.z = pk_bf16(av[4], av[5]);
            o4.w = pk_bf16(av[6], av[7]);
            *reinterpret_cast<uint4*>(&hs16[r][8 * ql]) = o4;
        }
    }
#undef LDB
#undef ADD8
    __syncthreads();

    // ---- phase 2: MFMA linear. wave wid handles col-tiles 2*wid, 2*wid+1 ----
    bf16x8 afrag[4];
    const int arow = lane & 15;
    const int acol0 = (lane >> 4) * 8;
    #pragma unroll
    for (int ks = 0; ks < 4; ++ks)
        afrag[ks] = *reinterpret_cast<const bf16x8*>(&hs16[arow][ks * 32 + acol0]);

    #pragma unroll
    for (int c2 = 0; c2 < 2; ++c2) {
        const int ct = wid * 2 + c2;
        f32x4 acc = {0.f, 0.f, 0.f, 0.f};
        #pragma unroll
        for (int ks = 0; ks < 4; ++ks) {
            bf16x8 bfrag = *reinterpret_cast<const bf16x8*>(
                Wb + ((size_t)(ct * 4 + ks) * 64 + lane) * 8);
            acc = __builtin_amdgcn_mfma_f32_16x16x32_bf16(afrag[ks], bfrag, acc, 0, 0, 0);
        }
        const int col = ct * 16 + (lane & 15);
        const float bb = bias[col];
        float psum = 0.0f, psq = 0.0f;
        #pragma unroll
        for (int i = 0; i < 4; ++i) {
            const int rrow = (lane >> 4) * 4 + i;   // C/D row mapping (m89)
            const int n = row0 + rrow;
            float v = (acc[i] + bb) * snorm[n];
            y[(size_t)n * D + col] = v;
            psum += v;
            psq += v * v;
        }
        psum += __shfl_xor(psum, 16, 64);
        psq  += __shfl_xor(psq, 16, 64);
        psum += __shfl_xor(psum, 32, 64);
        psq  += __shfl_xor(psq, 32, 64);
        if (lane < 16) {
            partial[(size_t)blockIdx.x * 256 + col] = psum;
            partial[(size_t)blockIdx.x * 256 + 128 + col] = psq;
        }
    }
}

// ---------------- reduce partials -> BN scale/shift per column ----------------
__global__ __launch_bounds__(256) void bn_reduce(const float* __restrict__ partial,
                                                 const float* __restrict__ gamma,
                                                 const float* __restrict__ beta,
                                                 float* __restrict__ bnparam,
                                                 int nchunk, float inv_n) {
    const int d = blockIdx.x;
    float s = 0.0f, q = 0.0f;
    for (int b = threadIdx.x; b < nchunk; b += 256) {
        s += partial[(size_t)b * 256 + d];
        q += partial[(size_t)b * 256 + 128 + d];
    }
    for (int off = 32; off > 0; off >>= 1) {
        s += __shfl_down(s, off, 64);
        q += __shfl_down(q, off, 64);
    }
    __shared__ float ss[4], qq[4];
    int wid = threadIdx.x >> 6;
    int lane = threadIdx.x & 63;
    if (lane == 0) { ss[wid] = s; qq[wid] = q; }
    __syncthreads();
    if (threadIdx.x == 0) {
        float S = ss[0] + ss[1] + ss[2] + ss[3];
        float Q = qq[0] + qq[1] + qq[2] + qq[3];
        float mu = S * inv_n;
        float var = Q * inv_n - mu * mu;
        var = fmaxf(var, 0.0f);
        float rstd = rsqrtf(var + BN_EPS);
        float scale = gamma[d] * rstd;
        float shift = beta[d] - mu * scale;
        bnparam[d] = scale;
        bnparam[D + d] = shift;
    }
}

// ---------------- finalize: out = feat + relu(y*scale + shift), in place on y --
__global__ __launch_bounds__(256) void finalize(const float* __restrict__ feat,
                                                float* __restrict__ y,
                                                const float* __restrict__ bnparam,
                                                int total4) {
    int i = blockIdx.x * 256 + threadIdx.x;
    if (i >= total4) return;
    int c = i & 31;
    float4 v = reinterpret_cast<float4*>(y)[i];
    float4 f = reinterpret_cast<const float4*>(feat)[i];
    float4 sc = reinterpret_cast<const float4*>(bnparam)[c];
    float4 sh = reinterpret_cast<const float4*>(bnparam + D)[c];
    v.x = f.x + fmaxf(v.x * sc.x + sh.x, 0.0f);
    v.y = f.y + fmaxf(v.y * sc.y + sh.y, 0.0f);
    v.z = f.z + fmaxf(v.z * sc.z + sh.z, 0.0f);
    v.w = f.w + fmaxf(v.w * sc.w + sh.w, 0.0f);
    reinterpret_cast<float4*>(y)[i] = v;
}

extern "C" void kernel_launch(void* const* d_in, const int* in_sizes, int n_in,
                              void* d_out, int out_size, void* d_ws, size_t ws_size,
                              hipStream_t stream) {
    const float* feat  = (const float*)d_in[0];
    const float* snorm = (const float*)d_in[1];
    const int*   src   = (const int*)d_in[2];
    const int*   dst   = (const int*)d_in[3];
    const float* W     = (const float*)d_in[4];
    const float* bias  = (const float*)d_in[5];
    const float* gamma = (const float*)d_in[6];
    const float* beta  = (const float*)d_in[7];

    const int N = in_sizes[1];              // 50000
    const int E = in_sizes[2];              // 1600000
    const int nblk = N / ROWS;              // 3125
    const int nch = (E + CHUNK - 1) / CHUNK;   // 196 (<= CAP_SCAN)
    const int nbuck = (N + 255) >> 8;          // 196
    const int ncast = (N * D) / (8 * 256);     // 3125

    // workspace layout (all segments 16B-aligned)
    int* count       = (int*)d_ws;                          // N
    int* offs        = count + N;                           // N
    int* blkcnt      = offs + N;                            // 256*nch
    int* gtot        = blkcnt + (size_t)256 * nch;          // 256
    int* bucket_base = gtot + 256;                          // 256
    int* bucket_cnt  = bucket_base + 256;                   // 256
    u32* gpacked     = (u32*)(bucket_cnt + 256);            // E
    u16* epos        = (u16*)(gpacked + E);                 // E
    u16* feat16      = epos + E;                            // N*D
    u16* Wb          = feat16 + (size_t)N * D;              // D*D (bf16)
    float* partial   = (float*)(Wb + D * D);                // nblk*256
    float* bnparam   = partial + (size_t)nblk * 256;        // 2*D

    float* y = (float*)d_out;

    prep<<<ncast + 8 + nch, 256, 0, stream>>>(feat, feat16, W, Wb, dst,
                                              blkcnt, ncast, nch, E);

    scanB1<<<256, CAP_SCAN, 0, stream>>>(blkcnt, gtot, nch);
    scanB2<<<1, 256, 0, stream>>>(gtot, bucket_base, bucket_cnt);

    passB<<<nch, 512, 0, stream>>>(src, dst, blkcnt, bucket_base, gpacked, nch, E);

    pass2<<<nbuck, 512, 0, stream>>>(gpacked, bucket_base, bucket_cnt,
                                     epos, count, offs, N);

    fused_agg_linear<<<nblk, 256, 0, stream>>>(feat, feat16, snorm, offs, count,
                                               epos, Wb, bias, y, partial);

    bn_reduce<<<D, 256, 0, stream>>>(partial, gamma, beta, bnparam,
                                     nblk, 1.0f / (float)N);

    {
        int total4 = N * D / 4;
        finalize<<<(total4 + 255) / 256, 256, 0, stream>>>(feat, y, bnparam, total4);
    }
}